// Round 2
// baseline (1575.265 us; speedup 1.0000x reference)
//
#include <hip/hip_runtime.h>

// ---------------------------------------------------------------------------
// Self_Attn f32 pipeline (workspace-lean variant, 73 MB of d_ws):
//   z  = antialiased bilinear 26->13 downsample of f5   (4-tap [1,3,3,1]/8)
//   pfpg = [f_w;g_w] @ x + bias            [B,128,169]
//   E  = pf^T @ pg                         [B,169,169]
//   E  = softmax_rows(E)                   (in-place)
//   E += h_w@f8 + h_b
//   E += u_w@z + u_b
//   out = gamma*(c_w@E + c_b) + x          [B,512,169]
// ---------------------------------------------------------------------------

#define NTOK 169
constexpr int BM = 64, BN = 64, BK = 32;

// Generic batched SGEMM:  C[b] (+)= A @ Bmat[b] + bias, with epilogues.
//   A element (m,k): (m<M1 ? A0 + m*a_rs : A1 + (m-M1)*a_rs) + b*a_bs + k*a_cs
//   Bmat element (k,n): Bmat + b*b_bs + k*NTOK + n
// EPI: 0 = store, 1 = add-accumulate, 2 = out = gamma*(v+bias) + Xres
template <int EPI>
__global__ __launch_bounds__(256) void gemm_kernel(
    const float* __restrict__ A0, const float* __restrict__ A1, long a_bs,
    int a_rs, int a_cs, const float* __restrict__ Bmat, long b_bs,
    const float* __restrict__ bias0, const float* __restrict__ bias1,
    float* __restrict__ C, long c_bs, int M, int M1, int K,
    const float* __restrict__ Xres, const float* __restrict__ gammap) {
  __shared__ float smem[BK * BM + BK * BN];  // As | Bs ; reused as C-bounce
  float* As = smem;            // [BK][BM], XOR-swizzled in m
  float* Bs = smem + BK * BM;  // [BK][BN]

  const int tid = threadIdx.x;
  const int tx = tid & 15, ty = tid >> 4;
  const int n0 = blockIdx.x * BN;
  const int m0 = blockIdx.y * BM;
  const int b = blockIdx.z;
  const float* Bb = Bmat + (long)b * b_bs;

  float acc[4][4] = {};

  for (int k0 = 0; k0 < K; k0 += BK) {
    __syncthreads();
    // ---- stage A tile (BM x BK = 2048 elems, 8/thread) ----
    if (a_cs == 1) {
      // row-major A: k-fast lanes -> coalesced along k
#pragma unroll
      for (int j = 0; j < 8; ++j) {
        int idx = tid + j * 256;
        int k = idx & (BK - 1), m = idx >> 5;
        int mg = m0 + m, kg = k0 + k;
        float v = 0.f;
        if (mg < M && kg < K) {
          const float* ap = (mg < M1) ? (A0 + (long)mg * a_rs)
                                      : (A1 + (long)(mg - M1) * a_rs);
          v = ap[(long)b * a_bs + kg];
        }
        As[k * BM + (m ^ ((k & 15) << 2))] = v;
      }
    } else {
      // col-major A (a_rs==1): m-fast lanes -> coalesced along m
#pragma unroll
      for (int j = 0; j < 8; ++j) {
        int idx = tid + j * 256;
        int m = idx & (BM - 1), k = idx >> 6;
        int mg = m0 + m, kg = k0 + k;
        float v = 0.f;
        if (mg < M && kg < K) {
          const float* ap =
              (mg < M1) ? (A0 + (long)mg) : (A1 + (long)(mg - M1));
          v = ap[(long)b * a_bs + (long)kg * a_cs];
        }
        As[k * BM + (m ^ ((k & 15) << 2))] = v;
      }
    }
    // ---- stage B tile (BK x BN = 2048 elems, 8/thread, n-fast) ----
#pragma unroll
    for (int j = 0; j < 8; ++j) {
      int idx = tid + j * 256;
      int n = idx & (BN - 1), k = idx >> 6;
      int ng = n0 + n, kg = k0 + k;
      Bs[k * BN + n] = (ng < NTOK && kg < K) ? Bb[(long)kg * NTOK + ng] : 0.f;
    }
    __syncthreads();
    // ---- 4x4 register-tile FMA over the chunk ----
#pragma unroll
    for (int kk = 0; kk < BK; ++kk) {
      const float4 a4 =
          *(const float4*)&As[kk * BM + ((ty * 4) ^ ((kk & 15) << 2))];
      const float4 b4 = *(const float4*)&Bs[kk * BN + tx * 4];
      const float av[4] = {a4.x, a4.y, a4.z, a4.w};
      const float bv[4] = {b4.x, b4.y, b4.z, b4.w};
#pragma unroll
      for (int i = 0; i < 4; ++i)
#pragma unroll
        for (int j = 0; j < 4; ++j)
          acc[i][j] = fmaf(av[i], bv[j], acc[i][j]);
    }
  }

  // ---- epilogue: bounce through LDS for coalesced global stores ----
  __syncthreads();
  float* Cb = smem;  // BM*BN = 4096 floats = exactly As+Bs
#pragma unroll
  for (int i = 0; i < 4; ++i) {
    *(float4*)&Cb[(ty * 4 + i) * BN + tx * 4] =
        make_float4(acc[i][0], acc[i][1], acc[i][2], acc[i][3]);
  }
  __syncthreads();
  const float g = (EPI == 2) ? *gammap : 0.f;
#pragma unroll
  for (int j = 0; j < 16; ++j) {
    int idx = tid + j * 256;
    int m = idx >> 6, n = idx & (BN - 1);
    int mg = m0 + m, ng = n0 + n;
    if (mg < M && ng < NTOK) {
      float v = Cb[idx];
      if (bias0) v += (mg < M1) ? bias0[mg] : bias1[mg - M1];
      long off = (long)b * c_bs + (long)mg * NTOK + ng;
      if (EPI == 0)
        C[off] = v;
      else if (EPI == 1)
        C[off] += v;
      else
        C[off] = g * v + Xres[off];
    }
  }
}

// jax.image.resize bilinear 26->13, antialias=True (default):
// separable 4-tap [1,3,3,1]/8 at taps {2i-1..2i+2}, edge-renormalized per axis.
__global__ __launch_bounds__(256) void pool_kernel(const float* __restrict__ f5,
                                                   float* __restrict__ z,
                                                   int total) {
  int id = blockIdx.x * 256 + threadIdx.x;
  if (id >= total) return;
  int n = id % 169;
  int bc = id / 169;
  int y = n / 13, x = n % 13;
  const float* src = f5 + (long)bc * 676;  // 26*26
  const float w4[4] = {0.125f, 0.375f, 0.375f, 0.125f};
  float sy = 0.f, sx = 0.f, acc = 0.f;
#pragma unroll
  for (int dx = 0; dx < 4; ++dx) {
    int jx = 2 * x - 1 + dx;
    if (jx >= 0 && jx < 26) sx += w4[dx];
  }
#pragma unroll
  for (int dy = 0; dy < 4; ++dy) {
    int jy = 2 * y - 1 + dy;
    if (jy < 0 || jy >= 26) continue;
    sy += w4[dy];
    float rowacc = 0.f;
#pragma unroll
    for (int dx = 0; dx < 4; ++dx) {
      int jx = 2 * x - 1 + dx;
      if (jx >= 0 && jx < 26) rowacc += w4[dx] * src[jy * 26 + jx];
    }
    acc += w4[dy] * rowacc;
  }
  z[id] = acc / (sy * sx);
}

// In-place row softmax of E (169 cols). One wave per row.
__global__ __launch_bounds__(256) void softmax_kernel(float* __restrict__ E,
                                                      int nrows) {
  int wave = threadIdx.x >> 6;
  int lane = threadIdx.x & 63;
  int row = blockIdx.x * 4 + wave;
  if (row >= nrows) return;
  float* e = E + (long)row * NTOK;
  float e0 = e[lane];
  float e1 = e[lane + 64];
  float e2 = (lane < 41) ? e[lane + 128] : -INFINITY;
  float m = fmaxf(fmaxf(e0, e1), e2);
#pragma unroll
  for (int o = 32; o; o >>= 1) m = fmaxf(m, __shfl_xor(m, o, 64));
  float p0 = __expf(e0 - m), p1 = __expf(e1 - m);
  float p2 = (lane < 41) ? __expf(e2 - m) : 0.f;
  float s = p0 + p1 + p2;
#pragma unroll
  for (int o = 32; o; o >>= 1) s += __shfl_xor(s, o, 64);
  float inv = 1.f / s;
  e[lane] = p0 * inv;
  e[lane + 64] = p1 * inv;
  if (lane < 41) e[lane + 128] = p2 * inv;
}

extern "C" void kernel_launch(void* const* d_in, const int* in_sizes, int n_in,
                              void* d_out, int out_size, void* d_ws,
                              size_t ws_size, hipStream_t stream) {
  const float* x = (const float*)d_in[0];
  const float* f5 = (const float*)d_in[1];
  const float* f8 = (const float*)d_in[2];
  const float* f_w = (const float*)d_in[3];
  const float* f_b = (const float*)d_in[4];
  const float* g_w = (const float*)d_in[5];
  const float* g_b = (const float*)d_in[6];
  const float* h_w = (const float*)d_in[7];
  const float* h_b = (const float*)d_in[8];
  const float* u_w = (const float*)d_in[9];
  const float* u_b = (const float*)d_in[10];
  const float* c_w = (const float*)d_in[11];
  const float* c_b = (const float*)d_in[12];
  const float* gamma = (const float*)d_in[13];
  float* out = (float*)d_out;

  const int B = 256;
  float* z = (float*)d_ws;                // [B,128,169]  22.1 MB
  float* pfpg = z + (long)B * 128 * 169;  // [B,128,169]  22.1 MB
  float* E = pfpg + (long)B * 128 * 169;  // [B,169,169]  29.2 MB
  // total d_ws use: 73.5 MB

  // 1) antialiased downsample f5 -> z
  int ptotal = B * 128 * 169;
  pool_kernel<<<dim3((ptotal + 255) / 256), dim3(256), 0, stream>>>(f5, z,
                                                                    ptotal);
  // 2) pf|pg = [f_w;g_w] @ x + [f_b;g_b]
  gemm_kernel<0><<<dim3(3, 2, B), dim3(256), 0, stream>>>(
      f_w, g_w, 0L, 512, 1, x, 512L * 169, f_b, g_b, pfpg, 128L * 169, 128, 64,
      512, nullptr, nullptr);
  // 3) E = pf^T @ pg   (A = pf, col-major strides, per-batch A)
  gemm_kernel<0><<<dim3(3, 3, B), dim3(256), 0, stream>>>(
      pfpg, pfpg, 128L * 169, 1, 169, pfpg + 64 * 169, 128L * 169, nullptr,
      nullptr, E, 169L * 169, 169, 169, 64, nullptr, nullptr);
  // 4) E = softmax_rows(E) in place
  int nrows = B * 169;
  softmax_kernel<<<dim3((nrows + 3) / 4), dim3(256), 0, stream>>>(E, nrows);
  // 5) E += h_w @ f8 + h_b
  gemm_kernel<1><<<dim3(3, 3, B), dim3(256), 0, stream>>>(
      h_w, h_w, 0L, 256, 1, f8, 256L * 169, h_b, h_b, E, 169L * 169, 169, 169,
      256, nullptr, nullptr);
  // 6) E += u_w @ z + u_b
  gemm_kernel<1><<<dim3(3, 3, B), dim3(256), 0, stream>>>(
      u_w, u_w, 0L, 128, 1, z, 128L * 169, u_b, u_b, E, 169L * 169, 169, 169,
      128, nullptr, nullptr);
  // 7) out = gamma*(c_w @ E + c_b) + x
  gemm_kernel<2><<<dim3(3, 8, B), dim3(256), 0, stream>>>(
      c_w, c_w, 0L, 169, 1, E, 169L * 169, c_b, c_b, out, 512L * 169, 512, 512,
      169, x, gamma);
}

// Round 3
// 1128.016 us; speedup vs baseline: 1.3965x; 1.3965x over previous
//
#include <hip/hip_runtime.h>

// ---------------------------------------------------------------------------
// Self_Attn bf16-MFMA pipeline (token-major). All MFMA = f32_16x16x32_bf16.
//   prep:  swz weights -> frag order bf16 (L2-resident, loaded direct)
//          pool f5 -> zb[b][t][128] bf16 (antialiased [1,3,3,1]/8 resize)
//          transpose-convert f8 -> f8b[b][t][256], x -> xb[b][t][512]
//   G3:    St[b][t][192] = f8z @ Whu^T + (h_b+u_b)        (k-concat 384)
//   G1:    P[b][t][128]  = xb @ Wfg^T + bias              (pf|pg)
//   G2:    Et[b][n][176] = P[:,:64] @ P[:,64:]^T  (f32)   (energy, K=64)
//   SMT:   St[m][n]     += softmax_row_n(Et)^T            (LDS transpose)
//   G4:    out[b][co][t] = gamma*(c_w @ St^T + c_b) + x   (K=192, pads 0)
// Workspace: 72.5 MB (proven-safe <= 73.5 MB), regions reused by lifetime.
// ---------------------------------------------------------------------------

typedef __attribute__((ext_vector_type(4))) float f32x4;
typedef __attribute__((ext_vector_type(8))) short short8;
union U16 { uint4 u; short8 s; ushort us[8]; };

__device__ inline ushort f2b(float f) {  // f32 -> bf16 RNE
  union { float f; uint u; } v{f};
  return (ushort)((v.u + 0x7fffu + ((v.u >> 16) & 1u)) >> 16);
}
__device__ inline float b2f(ushort h) {
  union { uint u; float f; } v{(uint)h << 16};
  return v.f;
}
__device__ inline f32x4 mfma(short8 a, short8 b, f32x4 c) {
  return __builtin_amdgcn_mfma_f32_16x16x32_bf16(a, b, c, 0, 0, 0);
}

// Stage ROWS x 64(bf16) tile into LDS, 16B chunks XOR-swizzled: chunk^=(row&7).
// src: row-major bf16, pre-offset to tile row 0; rows >= valid_rows -> 0.
template <int ROWS>
__device__ inline void stage(uint4* lds, const ushort* __restrict__ src,
                             int valid_rows, int row_stride, int k0) {
#pragma unroll
  for (int i = 0; i < (ROWS * 8 + 255) / 256; ++i) {
    int idx = threadIdx.x + i * 256;
    if ((ROWS * 8) % 256 == 0 || idx < ROWS * 8) {
      int row = idx >> 3, ch = idx & 7;
      uint4 v = make_uint4(0, 0, 0, 0);
      if (row < valid_rows)
        v = *(const uint4*)(src + row * row_stride + k0 + ch * 8);
      lds[(row << 3) | (ch ^ (row & 7))] = v;
    }
  }
}

// Read one 16x32 operand fragment (frag16-th 16-row group, ks-th k32 step).
__device__ inline short8 fragA(const uint4* lds, int frag, int ks, int lane) {
  int row = (frag << 4) | (lane & 15);
  int ch = ((ks << 2) | (lane >> 4)) ^ (row & 7);
  U16 t;
  t.u = lds[(row << 3) | ch];
  return t.s;
}
// Pre-swizzled weight fragment, direct from global (L2-resident).
__device__ inline short8 wfrag(const ushort* __restrict__ w, int frag, int s32,
                               int S32, int lane) {
  U16 t;
  t.u = *(const uint4*)(w + (((long)frag * S32 + s32) * 64 + lane) * 8);
  return t.s;
}

// ---- weight pre-swizzle: dst[f][s32][lane][8] = W[16f+(l&15)][32s+8(l>>4)+i]
__global__ __launch_bounds__(256) void swz_kernel(
    const float* __restrict__ s0, const float* __restrict__ s1,
    ushort* __restrict__ dst, int F, int S32, int mode) {
  int id = blockIdx.x * 256 + threadIdx.x;
  if (id >= F * S32 * 64) return;
  int l = id & 63, fs = id >> 6;
  int s = fs % S32, f = fs / S32;
  int co = f * 16 + (l & 15);
  int kb = s * 32 + 8 * (l >> 4);
  U16 t;
#pragma unroll
  for (int i = 0; i < 8; ++i) {
    int k = kb + i;
    float v = 0.f;
    if (mode == 0)  // Wfg: co<64 -> f_w[64][512] else g_w
      v = (co < 64) ? s0[co * 512 + k] : s1[(co - 64) * 512 + k];
    else if (mode == 1) {  // Whu: co<169 valid; k<256 -> h_w[169][256] else u_w[169][128]
      if (co < 169) v = (k < 256) ? s0[co * 256 + k] : s1[co * 128 + (k - 256)];
    } else {  // Wc: c_w[512][169], k-pad to 192
      if (k < 169) v = s0[co * 169 + k];
    }
    t.us[i] = f2b(v);
  }
  *(uint4*)(dst + (long)id * 8) = t.u;
}

// ---- pool: jax bilinear 26->13 antialias ([1,3,3,1]/8, edge-renormalized),
// token-major bf16 out. grid (169, B), block 128 (=channels).
__global__ void pool_kernel(const float* __restrict__ f5,
                            ushort* __restrict__ zb) {
  int t = blockIdx.x, b = blockIdx.y, c = threadIdx.x;
  int y = t / 13, xx = t % 13;
  const float* src = f5 + ((long)b * 128 + c) * 676;
  const float w4[4] = {0.125f, 0.375f, 0.375f, 0.125f};
  float sy = 0.f, sx = 0.f, acc = 0.f;
#pragma unroll
  for (int dx = 0; dx < 4; ++dx) {
    int jx = 2 * xx - 1 + dx;
    if (jx >= 0 && jx < 26) sx += w4[dx];
  }
#pragma unroll
  for (int dy = 0; dy < 4; ++dy) {
    int jy = 2 * y - 1 + dy;
    if (jy < 0 || jy >= 26) continue;
    sy += w4[dy];
    float rowacc = 0.f;
#pragma unroll
    for (int dx = 0; dx < 4; ++dx) {
      int jx = 2 * xx - 1 + dx;
      if (jx >= 0 && jx < 26) rowacc += w4[dx] * src[jy * 26 + jx];
    }
    acc += w4[dy] * rowacc;
  }
  zb[((long)b * 169 + t) * 128 + c] = f2b(acc / (sy * sx));
}

// ---- transpose+convert [C][169] f32 -> [169][C] bf16. grid (6, C/64, B).
__global__ __launch_bounds__(256) void tconv_kernel(const float* __restrict__ src,
                                                    ushort* __restrict__ dst,
                                                    int C) {
  __shared__ float lds[64 * 33];
  int t0 = blockIdx.x * 32, c0 = blockIdx.y * 64, b = blockIdx.z;
  int tid = threadIdx.x;
  int tl = tid & 31, ch = tid >> 5;
#pragma unroll
  for (int i = 0; i < 8; ++i) {
    int cl = i * 8 + ch;
    int t = t0 + tl;
    lds[cl * 33 + tl] = (t < 169) ? src[((long)b * C + c0 + cl) * 169 + t] : 0.f;
  }
  __syncthreads();
  int tok = tid >> 3, q = tid & 7;
  int t = t0 + tok;
  if (t < 169) {
    U16 tmp;
#pragma unroll
    for (int j = 0; j < 8; ++j) tmp.us[j] = f2b(lds[(q * 8 + j) * 33 + tok]);
    *(uint4*)(dst + ((long)b * 169 + t) * C + c0 + q * 8) = tmp.u;
  }
}

// ---- G1: P[t][128] = xb[t][512] @ Wfg + bias. grid (3, B).
__global__ __launch_bounds__(256) void g1_kernel(
    const ushort* __restrict__ xb, const ushort* __restrict__ wfg,
    const float* __restrict__ f_b, const float* __restrict__ g_b,
    ushort* __restrict__ P) {
  __shared__ uint4 lds[64 * 8];
  int t0 = blockIdx.x * 64, b = blockIdx.y;
  int lane = threadIdx.x & 63, w = threadIdx.x >> 6;
  const ushort* A = xb + ((long)b * 169 + t0) * 512;
  int valid = 169 - t0;
  f32x4 acc[4][2] = {};
  for (int k0 = 0; k0 < 512; k0 += 64) {
    __syncthreads();
    stage<64>(lds, A, valid, 512, k0);
    __syncthreads();
#pragma unroll
    for (int ks = 0; ks < 2; ++ks) {
      int s32 = (k0 >> 5) + ks;
      short8 bf0 = wfrag(wfg, 2 * w, s32, 16, lane);
      short8 bf1 = wfrag(wfg, 2 * w + 1, s32, 16, lane);
#pragma unroll
      for (int mf = 0; mf < 4; ++mf) {
        short8 af = fragA(lds, mf, ks, lane);
        acc[mf][0] = mfma(af, bf0, acc[mf][0]);
        acc[mf][1] = mfma(af, bf1, acc[mf][1]);
      }
    }
  }
  int ln = lane & 15, lg = lane >> 4;
#pragma unroll
  for (int mf = 0; mf < 4; ++mf)
#pragma unroll
    for (int j = 0; j < 2; ++j)
#pragma unroll
      for (int r = 0; r < 4; ++r) {
        int t = t0 + mf * 16 + 4 * lg + r;
        int c = w * 32 + j * 16 + ln;
        if (t < 169) {
          float bias = (c < 64) ? f_b[c] : g_b[c - 64];
          P[((long)b * 169 + t) * 128 + c] = f2b(acc[mf][j][r] + bias);
        }
      }
}

// ---- G2: Et[n][176] = P[:,0:64] @ P[:,64:128]^T (f32 out). grid (3, B).
__global__ __launch_bounds__(256) void g2_kernel(const ushort* __restrict__ P,
                                                 float* __restrict__ Et) {
  __shared__ uint4 lds[64 * 8 + 176 * 8];
  uint4* ldsA = lds;
  uint4* ldsB = lds + 64 * 8;
  int t0 = blockIdx.x * 64, b = blockIdx.y;
  int lane = threadIdx.x & 63, w = threadIdx.x >> 6;
  const ushort* Pb = P + (long)b * 169 * 128;
  stage<64>(ldsA, Pb + (long)t0 * 128, 169 - t0, 128, 0);
  stage<176>(ldsB, Pb + 64, 169, 128, 0);
  __syncthreads();
  f32x4 acc[11] = {};
#pragma unroll
  for (int ks = 0; ks < 2; ++ks) {
    short8 af = fragA(ldsA, w, ks, lane);
#pragma unroll
    for (int nf = 0; nf < 11; ++nf) {
      short8 bf = fragA(ldsB, nf, ks, lane);
      acc[nf] = mfma(af, bf, acc[nf]);
    }
  }
  int ln = lane & 15, lg = lane >> 4;
#pragma unroll
  for (int nf = 0; nf < 11; ++nf)
#pragma unroll
    for (int r = 0; r < 4; ++r) {
      int n = t0 + w * 16 + 4 * lg + r;
      int m = nf * 16 + ln;
      if (n < 169) Et[((long)b * 169 + n) * 176 + m] = acc[nf][r];
    }
}

// ---- G3: St[t][192] = [f8b|zb] @ Whu + (h_b+u_b). grid (3, B).
__global__ __launch_bounds__(256) void g3_kernel(
    const ushort* __restrict__ f8b, const ushort* __restrict__ zb,
    const ushort* __restrict__ whu, const float* __restrict__ h_b,
    const float* __restrict__ u_b, ushort* __restrict__ St) {
  __shared__ uint4 lds[64 * 8];
  int t0 = blockIdx.x * 64, b = blockIdx.y;
  int lane = threadIdx.x & 63, w = threadIdx.x >> 6;
  int valid = 169 - t0;
  const ushort* F = f8b + ((long)b * 169 + t0) * 256;
  const ushort* Z = zb + ((long)b * 169 + t0) * 128;
  f32x4 acc[4][3] = {};
  for (int k0 = 0; k0 < 384; k0 += 64) {
    __syncthreads();
#pragma unroll
    for (int i = 0; i < 2; ++i) {
      int idx = threadIdx.x + i * 256;
      int row = idx >> 3, ch = idx & 7;
      int k = k0 + ch * 8;
      uint4 v = make_uint4(0, 0, 0, 0);
      if (row < valid)
        v = (k < 256) ? *(const uint4*)(F + row * 256 + k)
                      : *(const uint4*)(Z + row * 128 + (k - 256));
      lds[(row << 3) | (ch ^ (row & 7))] = v;
    }
    __syncthreads();
#pragma unroll
    for (int ks = 0; ks < 2; ++ks) {
      int s32 = (k0 >> 5) + ks;
      short8 bf[3];
#pragma unroll
      for (int j = 0; j < 3; ++j) bf[j] = wfrag(whu, 3 * w + j, s32, 12, lane);
#pragma unroll
      for (int mf = 0; mf < 4; ++mf) {
        short8 af = fragA(lds, mf, ks, lane);
#pragma unroll
        for (int j = 0; j < 3; ++j) acc[mf][j] = mfma(af, bf[j], acc[mf][j]);
      }
    }
  }
  int ln = lane & 15, lg = lane >> 4;
#pragma unroll
  for (int mf = 0; mf < 4; ++mf)
#pragma unroll
    for (int j = 0; j < 3; ++j)
#pragma unroll
      for (int r = 0; r < 4; ++r) {
        int t = t0 + mf * 16 + 4 * lg + r;
        int co = w * 48 + j * 16 + ln;
        if (t < 169) {
          float bias = (co < 169) ? h_b[co] + u_b[co] : 0.f;
          St[((long)b * 169 + t) * 192 + co] = f2b(acc[mf][j][r] + bias);
        }
      }
}

// ---- SMT: St[m][n0..n0+31] += softmax-rows(Et)^T. grid (6, B).
__global__ __launch_bounds__(256) void smt_kernel(const float* __restrict__ Et,
                                                  ushort* __restrict__ St) {
  __shared__ float lds[32 * 178];
  int n0 = blockIdx.x * 32, b = blockIdx.y;
  int lane = threadIdx.x & 63, w = threadIdx.x >> 6;
#pragma unroll
  for (int j = 0; j < 8; ++j) {
    int nl = 4 * j + w;
    int n = n0 + nl;
    float p0 = 0.f, p1 = 0.f, p2 = 0.f;
    if (n < 169) {
      const float* e = Et + ((long)b * 169 + n) * 176;
      float e0 = e[lane], e1 = e[lane + 64];
      float e2 = (lane < 41) ? e[lane + 128] : -1e30f;
      float m = fmaxf(fmaxf(e0, e1), e2);
#pragma unroll
      for (int o = 32; o; o >>= 1) m = fmaxf(m, __shfl_xor(m, o, 64));
      p0 = __expf(e0 - m);
      p1 = __expf(e1 - m);
      p2 = (lane < 41) ? __expf(e2 - m) : 0.f;
      float s = p0 + p1 + p2;
#pragma unroll
      for (int o = 32; o; o >>= 1) s += __shfl_xor(s, o, 64);
      float inv = 1.f / s;
      p0 *= inv; p1 *= inv; p2 *= inv;
    }
    lds[nl * 178 + lane] = p0;
    lds[nl * 178 + 64 + lane] = p1;
    if (lane < 41) lds[nl * 178 + 128 + lane] = p2;
  }
  __syncthreads();
  int m = threadIdx.x;
  if (m < 169) {
    ushort* sp = St + ((long)b * 169 + m) * 192 + n0;
    uint4 cur[4];
#pragma unroll
    for (int q = 0; q < 4; ++q) cur[q] = *(const uint4*)(sp + q * 8);
    ushort* cu = (ushort*)cur;
#pragma unroll
    for (int q = 0; q < 32; ++q) cu[q] = f2b(b2f(cu[q]) + lds[q * 178 + m]);
#pragma unroll
    for (int q = 0; q < 4; ++q) *(uint4*)(sp + q * 8) = cur[q];
  }
}

// ---- G4: out[co][t] = gamma*(Wc @ St^T + c_b) + x. grid (4, B).
__global__ __launch_bounds__(256) void g4_kernel(
    const ushort* __restrict__ St, const ushort* __restrict__ wc,
    const float* __restrict__ c_b, const float* __restrict__ x,
    const float* __restrict__ gammap, float* __restrict__ out) {
  __shared__ uint4 lds[176 * 8];
  int m0 = blockIdx.x * 128, b = blockIdx.y;
  int lane = threadIdx.x & 63, w = threadIdx.x >> 6;
  const ushort* S = St + (long)b * 169 * 192;
  f32x4 acc[2][11] = {};
  for (int kt = 0; kt < 3; ++kt) {
    int k0 = kt * 64;
    __syncthreads();
    stage<176>(lds, S, 169, 192, k0);
    __syncthreads();
#pragma unroll
    for (int ks = 0; ks < 2; ++ks) {
      int s32 = kt * 2 + ks;
      short8 af0 = wfrag(wc, (m0 >> 4) + 2 * w, s32, 6, lane);
      short8 af1 = wfrag(wc, (m0 >> 4) + 2 * w + 1, s32, 6, lane);
#pragma unroll
      for (int nf = 0; nf < 11; ++nf) {
        short8 bf = fragA(lds, nf, ks, lane);
        acc[0][nf] = mfma(af0, bf, acc[0][nf]);
        acc[1][nf] = mfma(af1, bf, acc[1][nf]);
      }
    }
  }
  float g = *gammap;
  int ln = lane & 15, lg = lane >> 4;
#pragma unroll
  for (int i = 0; i < 2; ++i)
#pragma unroll
    for (int nf = 0; nf < 11; ++nf)
#pragma unroll
      for (int r = 0; r < 4; ++r) {
        int co = m0 + w * 32 + i * 16 + 4 * lg + r;
        int t = nf * 16 + ln;
        if (t < 169) {
          long off = ((long)b * 512 + co) * 169 + t;
          out[off] = g * (acc[i][nf][r] + c_b[co]) + x[off];
        }
      }
}

extern "C" void kernel_launch(void* const* d_in, const int* in_sizes, int n_in,
                              void* d_out, int out_size, void* d_ws,
                              size_t ws_size, hipStream_t stream) {
  const float* x = (const float*)d_in[0];
  const float* f5 = (const float*)d_in[1];
  const float* f8 = (const float*)d_in[2];
  const float* f_w = (const float*)d_in[3];
  const float* f_b = (const float*)d_in[4];
  const float* g_w = (const float*)d_in[5];
  const float* g_b = (const float*)d_in[6];
  const float* h_w = (const float*)d_in[7];
  const float* h_b = (const float*)d_in[8];
  const float* u_w = (const float*)d_in[9];
  const float* u_b = (const float*)d_in[10];
  const float* c_w = (const float*)d_in[11];
  const float* c_b = (const float*)d_in[12];
  const float* gamma = (const float*)d_in[13];
  float* out = (float*)d_out;

  char* ws = (char*)d_ws;
  // weights (frag-swizzled bf16)
  ushort* Wfg = (ushort*)(ws);            // 128*512*2  = 131072
  ushort* Whu = (ushort*)(ws + 131072);   // 192*384*2  = 147456
  ushort* Wc = (ushort*)(ws + 278528);    // 512*192*2  = 196608 (end 475136)
  // R1 (44.3MB): f8b -> xb -> Et (sequential lifetimes)
  char* R1 = ws + 524288;
  ushort* f8b = (ushort*)R1;   // 256*169*256*2 = 22,151,168
  ushort* xb = (ushort*)R1;    // 256*169*512*2 = 44,302,336
  float* Et = (float*)R1;      // 256*169*176*4 = 30,457,856
  // R2 (11.1MB): zb -> P
  char* R2 = ws + 524288 + 44302336;
  ushort* zb = (ushort*)R2;    // 256*169*128*2 = 11,075,584
  ushort* P = (ushort*)R2;
  // R3 (16.6MB): St
  char* R3 = ws + 524288 + 44302336 + 11075584;
  ushort* St = (ushort*)R3;    // 256*169*192*2 = 16,613,376  (total 72.5MB)

  const int B = 256;
  // weight swizzle
  swz_kernel<<<dim3(32), dim3(256), 0, stream>>>(f_w, g_w, Wfg, 8, 16, 0);
  swz_kernel<<<dim3(36), dim3(256), 0, stream>>>(h_w, u_w, Whu, 12, 12, 1);
  swz_kernel<<<dim3(48), dim3(256), 0, stream>>>(c_w, c_w, Wc, 32, 6, 2);
  // pool -> zb (token-major bf16)
  pool_kernel<<<dim3(169, B), dim3(128), 0, stream>>>(f5, zb);
  // f8 -> f8b
  tconv_kernel<<<dim3(6, 4, B), dim3(256), 0, stream>>>(f8, f8b, 256);
  // St = h+u projections (must finish before xb overwrites f8b's region)
  g3_kernel<<<dim3(3, B), dim3(256), 0, stream>>>(f8b, zb, Whu, h_b, u_b, St);
  // x -> xb (reuses R1; f8b dead)
  tconv_kernel<<<dim3(6, 8, B), dim3(256), 0, stream>>>(x, xb, 512);
  // P = pf|pg (reuses R2; zb dead)
  g1_kernel<<<dim3(3, B), dim3(256), 0, stream>>>(xb, Wfg, f_b, g_b, P);
  // Et = energy (reuses R1; xb dead)
  g2_kernel<<<dim3(3, B), dim3(256), 0, stream>>>(P, Et);
  // St += softmax(Et)^T
  smt_kernel<<<dim3(6, B), dim3(256), 0, stream>>>(Et, St);
  // out = gamma*(Wc@St^T + c_b) + x
  g4_kernel<<<dim3(4, B), dim3(256), 0, stream>>>(St, Wc, c_b, x, gamma, out);
}

// Round 6
// 449.139 us; speedup vs baseline: 3.5073x; 2.5115x over previous
//
#include <hip/hip_runtime.h>

// ---------------------------------------------------------------------------
// Self_Attn bf16-MFMA pipeline (token-major). All MFMA = f32_16x16x32_bf16.
//   prep:  swz weights -> frag order bf16 (L2-resident, loaded direct)
//          pool f5 -> zb[b][t][128] bf16 (antialiased [1,3,3,1]/8 resize)
//          transpose-convert f8 -> f8b[b][t][256], x -> xb[b][t][512]
//   G3:    St[b][t][192] = f8z @ Whu^T + (h_b+u_b)        (k-concat 384)
//   G1:    P[b][t][128]  = xb @ Wfg^T + bias              (pf|pg)
//   G2:    Et[b][n][176] = P[:,:64] @ P[:,64:]^T  (f32)   (energy, K=64)
//   SMT:   St[m][n]     += softmax_row_n(Et)^T            (LDS transpose)
//   G4:    out[b][co][t] = gamma*(c_w @ St^T + c_b) + x   (K=192, pads 0)
// R3->R4: pool_kernel rewritten LDS-staged & coalesced (was 2.6GB overfetch).
// R4->R6: identical resubmissions (GPU acquisition timeouts; kernel never ran).
// ---------------------------------------------------------------------------

typedef __attribute__((ext_vector_type(4))) float f32x4;
typedef __attribute__((ext_vector_type(8))) short short8;
union U16 { uint4 u; short8 s; ushort us[8]; };

__device__ inline ushort f2b(float f) {  // f32 -> bf16 RNE
  union { float f; uint u; } v{f};
  return (ushort)((v.u + 0x7fffu + ((v.u >> 16) & 1u)) >> 16);
}
__device__ inline float b2f(ushort h) {
  union { uint u; float f; } v{(uint)h << 16};
  return v.f;
}
__device__ inline f32x4 mfma(short8 a, short8 b, f32x4 c) {
  return __builtin_amdgcn_mfma_f32_16x16x32_bf16(a, b, c, 0, 0, 0);
}

// Stage ROWS x 64(bf16) tile into LDS, 16B chunks XOR-swizzled: chunk^=(row&7).
template <int ROWS>
__device__ inline void stage(uint4* lds, const ushort* __restrict__ src,
                             int valid_rows, int row_stride, int k0) {
#pragma unroll
  for (int i = 0; i < (ROWS * 8 + 255) / 256; ++i) {
    int idx = threadIdx.x + i * 256;
    if ((ROWS * 8) % 256 == 0 || idx < ROWS * 8) {
      int row = idx >> 3, ch = idx & 7;
      uint4 v = make_uint4(0, 0, 0, 0);
      if (row < valid_rows)
        v = *(const uint4*)(src + row * row_stride + k0 + ch * 8);
      lds[(row << 3) | (ch ^ (row & 7))] = v;
    }
  }
}

// Read one 16x32 operand fragment (frag16-th 16-row group, ks-th k32 step).
__device__ inline short8 fragA(const uint4* lds, int frag, int ks, int lane) {
  int row = (frag << 4) | (lane & 15);
  int ch = ((ks << 2) | (lane >> 4)) ^ (row & 7);
  U16 t;
  t.u = lds[(row << 3) | ch];
  return t.s;
}
// Pre-swizzled weight fragment, direct from global (L2-resident).
__device__ inline short8 wfrag(const ushort* __restrict__ w, int frag, int s32,
                               int S32, int lane) {
  U16 t;
  t.u = *(const uint4*)(w + (((long)frag * S32 + s32) * 64 + lane) * 8);
  return t.s;
}

// ---- weight pre-swizzle: dst[f][s32][lane][8] = W[16f+(l&15)][32s+8(l>>4)+i]
__global__ __launch_bounds__(256) void swz_kernel(
    const float* __restrict__ s0, const float* __restrict__ s1,
    ushort* __restrict__ dst, int F, int S32, int mode) {
  int id = blockIdx.x * 256 + threadIdx.x;
  if (id >= F * S32 * 64) return;
  int l = id & 63, fs = id >> 6;
  int s = fs % S32, f = fs / S32;
  int co = f * 16 + (l & 15);
  int kb = s * 32 + 8 * (l >> 4);
  U16 t;
#pragma unroll
  for (int i = 0; i < 8; ++i) {
    int k = kb + i;
    float v = 0.f;
    if (mode == 0)
      v = (co < 64) ? s0[co * 512 + k] : s1[(co - 64) * 512 + k];
    else if (mode == 1) {
      if (co < 169) v = (k < 256) ? s0[co * 256 + k] : s1[co * 128 + (k - 256)];
    } else {
      if (k < 169) v = s0[co * 169 + k];
    }
    t.us[i] = f2b(v);
  }
  *(uint4*)(dst + (long)id * 8) = t.u;
}

// ---- pool: jax bilinear 26->13 antialias ([1,3,3,1]/8, edge-renormalized).
// LDS-staged, coalesced. Block = (b, 16-channel group); grid (B*8).
__global__ __launch_bounds__(256) void pool_kernel(const float* __restrict__ f5,
                                                   ushort* __restrict__ zb) {
  __shared__ float lds[16 * 676];  // 43.3 KB
  const int b = blockIdx.x >> 3, cg = blockIdx.x & 7;
  const int tid = threadIdx.x;
  // coalesced load of the 16-channel slab (contiguous 10816 floats)
  const float4* src4 = (const float4*)(f5 + ((long)b * 128 + cg * 16) * 676);
#pragma unroll
  for (int i = 0; i < 11; ++i) {
    int idx = tid + i * 256;
    if (idx < 2704) ((float4*)lds)[idx] = src4[idx];
  }
  __syncthreads();
  const float w4[4] = {0.125f, 0.375f, 0.375f, 0.125f};
  const int c = tid & 15;
  const float* ch = lds + c * 676;
#pragma unroll
  for (int rep = 0; rep < 11; ++rep) {
    int t = rep * 16 + (tid >> 4);
    if (t >= 169) break;
    int y = t / 13, xx = t % 13;
    float sy = 0.f, sx = 0.f, acc = 0.f;
#pragma unroll
    for (int dx = 0; dx < 4; ++dx) {
      int jx = 2 * xx - 1 + dx;
      if (jx >= 0 && jx < 26) sx += w4[dx];
    }
#pragma unroll
    for (int dy = 0; dy < 4; ++dy) {
      int jy = 2 * y - 1 + dy;
      if (jy < 0 || jy >= 26) continue;
      sy += w4[dy];
      float rowacc = 0.f;
#pragma unroll
      for (int dx = 0; dx < 4; ++dx) {
        int jx = 2 * xx - 1 + dx;
        if (jx >= 0 && jx < 26) rowacc += w4[dx] * ch[jy * 26 + jx];
      }
      acc += w4[dy] * rowacc;
    }
    zb[((long)b * 169 + t) * 128 + cg * 16 + c] = f2b(acc / (sy * sx));
  }
}

// ---- transpose+convert [C][169] f32 -> [169][C] bf16. grid (6, C/64, B).
__global__ __launch_bounds__(256) void tconv_kernel(const float* __restrict__ src,
                                                    ushort* __restrict__ dst,
                                                    int C) {
  __shared__ float lds[64 * 33];
  int t0 = blockIdx.x * 32, c0 = blockIdx.y * 64, b = blockIdx.z;
  int tid = threadIdx.x;
  int tl = tid & 31, ch = tid >> 5;
#pragma unroll
  for (int i = 0; i < 8; ++i) {
    int cl = i * 8 + ch;
    int t = t0 + tl;
    lds[cl * 33 + tl] = (t < 169) ? src[((long)b * C + c0 + cl) * 169 + t] : 0.f;
  }
  __syncthreads();
  int tok = tid >> 3, q = tid & 7;
  int t = t0 + tok;
  if (t < 169) {
    U16 tmp;
#pragma unroll
    for (int j = 0; j < 8; ++j) tmp.us[j] = f2b(lds[(q * 8 + j) * 33 + tok]);
    *(uint4*)(dst + ((long)b * 169 + t) * C + c0 + q * 8) = tmp.u;
  }
}

// ---- G1: P[t][128] = xb[t][512] @ Wfg + bias. grid (3, B).
__global__ __launch_bounds__(256) void g1_kernel(
    const ushort* __restrict__ xb, const ushort* __restrict__ wfg,
    const float* __restrict__ f_b, const float* __restrict__ g_b,
    ushort* __restrict__ P) {
  __shared__ uint4 lds[64 * 8];
  int t0 = blockIdx.x * 64, b = blockIdx.y;
  int lane = threadIdx.x & 63, w = threadIdx.x >> 6;
  const ushort* A = xb + ((long)b * 169 + t0) * 512;
  int valid = 169 - t0;
  f32x4 acc[4][2] = {};
  for (int k0 = 0; k0 < 512; k0 += 64) {
    __syncthreads();
    stage<64>(lds, A, valid, 512, k0);
    __syncthreads();
#pragma unroll
    for (int ks = 0; ks < 2; ++ks) {
      int s32 = (k0 >> 5) + ks;
      short8 bf0 = wfrag(wfg, 2 * w, s32, 16, lane);
      short8 bf1 = wfrag(wfg, 2 * w + 1, s32, 16, lane);
#pragma unroll
      for (int mf = 0; mf < 4; ++mf) {
        short8 af = fragA(lds, mf, ks, lane);
        acc[mf][0] = mfma(af, bf0, acc[mf][0]);
        acc[mf][1] = mfma(af, bf1, acc[mf][1]);
      }
    }
  }
  int ln = lane & 15, lg = lane >> 4;
#pragma unroll
  for (int mf = 0; mf < 4; ++mf)
#pragma unroll
    for (int j = 0; j < 2; ++j)
#pragma unroll
      for (int r = 0; r < 4; ++r) {
        int t = t0 + mf * 16 + 4 * lg + r;
        int c = w * 32 + j * 16 + ln;
        if (t < 169) {
          float bias = (c < 64) ? f_b[c] : g_b[c - 64];
          P[((long)b * 169 + t) * 128 + c] = f2b(acc[mf][j][r] + bias);
        }
      }
}

// ---- G2: Et[n][176] = P[:,0:64] @ P[:,64:128]^T (f32 out). grid (3, B).
__global__ __launch_bounds__(256) void g2_kernel(const ushort* __restrict__ P,
                                                 float* __restrict__ Et) {
  __shared__ uint4 lds[64 * 8 + 176 * 8];
  uint4* ldsA = lds;
  uint4* ldsB = lds + 64 * 8;
  int t0 = blockIdx.x * 64, b = blockIdx.y;
  int lane = threadIdx.x & 63, w = threadIdx.x >> 6;
  const ushort* Pb = P + (long)b * 169 * 128;
  stage<64>(ldsA, Pb + (long)t0 * 128, 169 - t0, 128, 0);
  stage<176>(ldsB, Pb + 64, 169, 128, 0);
  __syncthreads();
  f32x4 acc[11] = {};
#pragma unroll
  for (int ks = 0; ks < 2; ++ks) {
    short8 af = fragA(ldsA, w, ks, lane);
#pragma unroll
    for (int nf = 0; nf < 11; ++nf) {
      short8 bf = fragA(ldsB, nf, ks, lane);
      acc[nf] = mfma(af, bf, acc[nf]);
    }
  }
  int ln = lane & 15, lg = lane >> 4;
#pragma unroll
  for (int nf = 0; nf < 11; ++nf)
#pragma unroll
    for (int r = 0; r < 4; ++r) {
      int n = t0 + w * 16 + 4 * lg + r;
      int m = nf * 16 + ln;
      if (n < 169) Et[((long)b * 169 + n) * 176 + m] = acc[nf][r];
    }
}

// ---- G3: St[t][192] = [f8b|zb] @ Whu + (h_b+u_b). grid (3, B).
__global__ __launch_bounds__(256) void g3_kernel(
    const ushort* __restrict__ f8b, const ushort* __restrict__ zb,
    const ushort* __restrict__ whu, const float* __restrict__ h_b,
    const float* __restrict__ u_b, ushort* __restrict__ St) {
  __shared__ uint4 lds[64 * 8];
  int t0 = blockIdx.x * 64, b = blockIdx.y;
  int lane = threadIdx.x & 63, w = threadIdx.x >> 6;
  int valid = 169 - t0;
  const ushort* F = f8b + ((long)b * 169 + t0) * 256;
  const ushort* Z = zb + ((long)b * 169 + t0) * 128;
  f32x4 acc[4][3] = {};
  for (int k0 = 0; k0 < 384; k0 += 64) {
    __syncthreads();
#pragma unroll
    for (int i = 0; i < 2; ++i) {
      int idx = threadIdx.x + i * 256;
      int row = idx >> 3, ch = idx & 7;
      int k = k0 + ch * 8;
      uint4 v = make_uint4(0, 0, 0, 0);
      if (row < valid)
        v = (k < 256) ? *(const uint4*)(F + row * 256 + k)
                      : *(const uint4*)(Z + row * 128 + (k - 256));
      lds[(row << 3) | (ch ^ (row & 7))] = v;
    }
    __syncthreads();
#pragma unroll
    for (int ks = 0; ks < 2; ++ks) {
      int s32 = (k0 >> 5) + ks;
      short8 bf[3];
#pragma unroll
      for (int j = 0; j < 3; ++j) bf[j] = wfrag(whu, 3 * w + j, s32, 12, lane);
#pragma unroll
      for (int mf = 0; mf < 4; ++mf) {
        short8 af = fragA(lds, mf, ks, lane);
#pragma unroll
        for (int j = 0; j < 3; ++j) acc[mf][j] = mfma(af, bf[j], acc[mf][j]);
      }
    }
  }
  int ln = lane & 15, lg = lane >> 4;
#pragma unroll
  for (int mf = 0; mf < 4; ++mf)
#pragma unroll
    for (int j = 0; j < 3; ++j)
#pragma unroll
      for (int r = 0; r < 4; ++r) {
        int t = t0 + mf * 16 + 4 * lg + r;
        int co = w * 48 + j * 16 + ln;
        if (t < 169) {
          float bias = (co < 169) ? h_b[co] + u_b[co] : 0.f;
          St[((long)b * 169 + t) * 192 + co] = f2b(acc[mf][j][r] + bias);
        }
      }
}

// ---- SMT: St[m][n0..n0+31] += softmax-rows(Et)^T. grid (6, B).
__global__ __launch_bounds__(256) void smt_kernel(const float* __restrict__ Et,
                                                  ushort* __restrict__ St) {
  __shared__ float lds[32 * 178];
  int n0 = blockIdx.x * 32, b = blockIdx.y;
  int lane = threadIdx.x & 63, w = threadIdx.x >> 6;
#pragma unroll
  for (int j = 0; j < 8; ++j) {
    int nl = 4 * j + w;
    int n = n0 + nl;
    float p0 = 0.f, p1 = 0.f, p2 = 0.f;
    if (n < 169) {
      const float* e = Et + ((long)b * 169 + n) * 176;
      float e0 = e[lane], e1 = e[lane + 64];
      float e2 = (lane < 41) ? e[lane + 128] : -1e30f;
      float m = fmaxf(fmaxf(e0, e1), e2);
#pragma unroll
      for (int o = 32; o; o >>= 1) m = fmaxf(m, __shfl_xor(m, o, 64));
      p0 = __expf(e0 - m);
      p1 = __expf(e1 - m);
      p2 = (lane < 41) ? __expf(e2 - m) : 0.f;
      float s = p0 + p1 + p2;
#pragma unroll
      for (int o = 32; o; o >>= 1) s += __shfl_xor(s, o, 64);
      float inv = 1.f / s;
      p0 *= inv; p1 *= inv; p2 *= inv;
    }
    lds[nl * 178 + lane] = p0;
    lds[nl * 178 + 64 + lane] = p1;
    if (lane < 41) lds[nl * 178 + 128 + lane] = p2;
  }
  __syncthreads();
  int m = threadIdx.x;
  if (m < 169) {
    ushort* sp = St + ((long)b * 169 + m) * 192 + n0;
    uint4 cur[4];
#pragma unroll
    for (int q = 0; q < 4; ++q) cur[q] = *(const uint4*)(sp + q * 8);
    ushort* cu = (ushort*)cur;
#pragma unroll
    for (int q = 0; q < 32; ++q) cu[q] = f2b(b2f(cu[q]) + lds[q * 178 + m]);
#pragma unroll
    for (int q = 0; q < 4; ++q) *(uint4*)(sp + q * 8) = cur[q];
  }
}

// ---- G4: out[co][t] = gamma*(Wc @ St^T + c_b) + x. grid (4, B).
__global__ __launch_bounds__(256) void g4_kernel(
    const ushort* __restrict__ St, const ushort* __restrict__ wc,
    const float* __restrict__ c_b, const float* __restrict__ x,
    const float* __restrict__ gammap, float* __restrict__ out) {
  __shared__ uint4 lds[176 * 8];
  int m0 = blockIdx.x * 128, b = blockIdx.y;
  int lane = threadIdx.x & 63, w = threadIdx.x >> 6;
  const ushort* S = St + (long)b * 169 * 192;
  f32x4 acc[2][11] = {};
  for (int kt = 0; kt < 3; ++kt) {
    int k0 = kt * 64;
    __syncthreads();
    stage<176>(lds, S, 169, 192, k0);
    __syncthreads();
#pragma unroll
    for (int ks = 0; ks < 2; ++ks) {
      int s32 = kt * 2 + ks;
      short8 af0 = wfrag(wc, (m0 >> 4) + 2 * w, s32, 6, lane);
      short8 af1 = wfrag(wc, (m0 >> 4) + 2 * w + 1, s32, 6, lane);
#pragma unroll
      for (int nf = 0; nf < 11; ++nf) {
        short8 bf = fragA(lds, nf, ks, lane);
        acc[0][nf] = mfma(af0, bf, acc[0][nf]);
        acc[1][nf] = mfma(af1, bf, acc[1][nf]);
      }
    }
  }
  float g = *gammap;
  int ln = lane & 15, lg = lane >> 4;
#pragma unroll
  for (int i = 0; i < 2; ++i)
#pragma unroll
    for (int nf = 0; nf < 11; ++nf)
#pragma unroll
      for (int r = 0; r < 4; ++r) {
        int co = m0 + w * 32 + i * 16 + 4 * lg + r;
        int t = nf * 16 + ln;
        if (t < 169) {
          long off = ((long)b * 512 + co) * 169 + t;
          out[off] = g * (acc[i][nf][r] + c_b[co]) + x[off];
        }
      }
}

extern "C" void kernel_launch(void* const* d_in, const int* in_sizes, int n_in,
                              void* d_out, int out_size, void* d_ws,
                              size_t ws_size, hipStream_t stream) {
  const float* x = (const float*)d_in[0];
  const float* f5 = (const float*)d_in[1];
  const float* f8 = (const float*)d_in[2];
  const float* f_w = (const float*)d_in[3];
  const float* f_b = (const float*)d_in[4];
  const float* g_w = (const float*)d_in[5];
  const float* g_b = (const float*)d_in[6];
  const float* h_w = (const float*)d_in[7];
  const float* h_b = (const float*)d_in[8];
  const float* u_w = (const float*)d_in[9];
  const float* u_b = (const float*)d_in[10];
  const float* c_w = (const float*)d_in[11];
  const float* c_b = (const float*)d_in[12];
  const float* gamma = (const float*)d_in[13];
  float* out = (float*)d_out;

  char* ws = (char*)d_ws;
  ushort* Wfg = (ushort*)(ws);           // 128*512*2  = 131072
  ushort* Whu = (ushort*)(ws + 131072);  // 192*384*2  = 147456
  ushort* Wc = (ushort*)(ws + 278528);   // 512*192*2  = 196608 (end 475136)
  char* R1 = ws + 524288;                // f8b -> xb -> Et
  ushort* f8b = (ushort*)R1;
  ushort* xb = (ushort*)R1;
  float* Et = (float*)R1;
  char* R2 = ws + 524288 + 44302336;     // zb -> P
  ushort* zb = (ushort*)R2;
  ushort* P = (ushort*)R2;
  char* R3 = ws + 524288 + 44302336 + 11075584;
  ushort* St = (ushort*)R3;              // total 72.5MB

  const int B = 256;
  swz_kernel<<<dim3(32), dim3(256), 0, stream>>>(f_w, g_w, Wfg, 8, 16, 0);
  swz_kernel<<<dim3(36), dim3(256), 0, stream>>>(h_w, u_w, Whu, 12, 12, 1);
  swz_kernel<<<dim3(48), dim3(256), 0, stream>>>(c_w, c_w, Wc, 32, 6, 2);
  pool_kernel<<<dim3(B * 8), dim3(256), 0, stream>>>(f5, zb);
  tconv_kernel<<<dim3(6, 4, B), dim3(256), 0, stream>>>(f8, f8b, 256);
  g3_kernel<<<dim3(3, B), dim3(256), 0, stream>>>(f8b, zb, Whu, h_b, u_b, St);
  tconv_kernel<<<dim3(6, 8, B), dim3(256), 0, stream>>>(x, xb, 512);
  g1_kernel<<<dim3(3, B), dim3(256), 0, stream>>>(xb, Wfg, f_b, g_b, P);
  g2_kernel<<<dim3(3, B), dim3(256), 0, stream>>>(P, Et);
  smt_kernel<<<dim3(6, B), dim3(256), 0, stream>>>(Et, St);
  g4_kernel<<<dim3(4, B), dim3(256), 0, stream>>>(St, Wc, c_b, x, gamma, out);
}